// Round 2
// baseline (150.705 us; speedup 1.0000x reference)
//
#include <hip/hip_runtime.h>
#include <math.h>

#define KMAX   32
#define CIN    64
#define COUT   64
#define NKERN  27
#define PPW    4          // points per wave
constexpr float BN_EPS = 1e-5f;

// ---------------- kernel 0: zero the stats accumulator ----------------
__global__ void k_zero(float* stats) {
    stats[threadIdx.x] = 0.0f;   // 128 threads: [0..63]=sum, [64..127]=sumsq
}

// ---------------- kernel 1: gather-conv + 64x64 matmul + relu --------
// Each wave: 4 points. Gathers unrolled x4 (4 rows in flight).
// dw held per-lane in registers (lane j owns dw[:,j]); sp broadcast via LDS.
__global__ __launch_bounds__(256, 4) void k_conv(
    const float* __restrict__ inputs,      // [N, 64]
    const float* __restrict__ sw,          // [27, 64, 1]
    const float* __restrict__ dw,          // [64, 64]
    const float* __restrict__ bias,        // [1, 64]
    const int*   __restrict__ nn_count,    // [N]
    const int*   __restrict__ nn_index,    // [N, 32]
    const int*   __restrict__ filt_index,  // [N, 32]
    float*       __restrict__ xout,        // [N, 64]  pre-BN (relu'd)
    float*       __restrict__ stats)       // [128]
{
    __shared__ float sw_lds[NKERN * CIN];   // 6.75 KB
    __shared__ float dw_stage[CIN * COUT];  // 16 KB (init staging only)
    __shared__ float sp_lds[4][CIN];        // per-wave sp broadcast, 1 KB
    __shared__ float red[2][4][COUT];       // stats reduction, 2 KB

    const int tid = threadIdx.x;
    for (int i = tid; i < NKERN * CIN; i += 256) sw_lds[i] = sw[i];
    for (int i = tid; i < CIN * COUT; i += 256) dw_stage[i] = dw[i];
    __syncthreads();

    const int wave = tid >> 6;
    const int lane = tid & 63;

    // lane j holds column j of dw in registers (statically indexed -> VGPRs)
    float dwr[CIN];
    #pragma unroll
    for (int c = 0; c < CIN; ++c) dwr[c] = dw_stage[c * COUT + lane];

    const int base = blockIdx.x * (4 * PPW) + wave * PPW;
    const float b = bias[lane];
    float sum = 0.0f, sumsq = 0.0f;

    #pragma unroll
    for (int p = 0; p < PPW; ++p) {
        const int n   = base + p;
        const int cnt = nn_count[n];
        const int* __restrict__ ni = nn_index   + (size_t)n * KMAX;
        const int* __restrict__ fi = filt_index + (size_t)n * KMAX;

        float a0 = 0.f, a1 = 0.f, a2 = 0.f, a3 = 0.f;
        int k = 0;
        for (; k + 4 <= cnt; k += 4) {
            const int i0 = ni[k], i1 = ni[k + 1], i2 = ni[k + 2], i3 = ni[k + 3];
            const int f0 = fi[k], f1 = fi[k + 1], f2 = fi[k + 2], f3 = fi[k + 3];
            const float g0 = inputs[(size_t)i0 * CIN + lane];
            const float g1 = inputs[(size_t)i1 * CIN + lane];
            const float g2 = inputs[(size_t)i2 * CIN + lane];
            const float g3 = inputs[(size_t)i3 * CIN + lane];
            a0 = fmaf(g0, sw_lds[f0 * CIN + lane], a0);
            a1 = fmaf(g1, sw_lds[f1 * CIN + lane], a1);
            a2 = fmaf(g2, sw_lds[f2 * CIN + lane], a2);
            a3 = fmaf(g3, sw_lds[f3 * CIN + lane], a3);
        }
        for (; k < cnt; ++k)
            a0 = fmaf(inputs[(size_t)ni[k] * CIN + lane],
                      sw_lds[fi[k] * CIN + lane], a0);

        const float spv = (a0 + a1 + a2 + a3) / (float)cnt;

        // broadcast sp across wave via LDS (wave-lockstep, no barrier)
        sp_lds[wave][lane] = spv;
        const float4* sp4 = (const float4*)sp_lds[wave];
        float xv = b;
        #pragma unroll
        for (int c4 = 0; c4 < CIN / 4; ++c4) {
            const float4 s4 = sp4[c4];           // broadcast read
            xv = fmaf(s4.x, dwr[c4 * 4 + 0], xv);
            xv = fmaf(s4.y, dwr[c4 * 4 + 1], xv);
            xv = fmaf(s4.z, dwr[c4 * 4 + 2], xv);
            xv = fmaf(s4.w, dwr[c4 * 4 + 3], xv);
        }
        xv = fmaxf(xv, 0.0f);

        xout[(size_t)n * COUT + lane] = xv;
        sum   += xv;
        sumsq += xv * xv;
    }

    red[0][wave][lane] = sum;
    red[1][wave][lane] = sumsq;
    __syncthreads();
    if (wave == 0) {
        float s = red[0][0][lane] + red[0][1][lane] + red[0][2][lane] + red[0][3][lane];
        float q = red[1][0][lane] + red[1][1][lane] + red[1][2][lane] + red[1][3][lane];
        atomicAdd(&stats[lane], s);
        atomicAdd(&stats[COUT + lane], q);
    }
}

// ---------------- kernel 2: finalize BN scale/shift -------------------
__global__ void k_finalize(const float* __restrict__ stats,
                           const float* __restrict__ gamma,
                           const float* __restrict__ beta,
                           float* __restrict__ sc_sh, float invN) {
    const int j = threadIdx.x;               // 64 threads
    const float mean = stats[j] * invN;
    const float var  = stats[COUT + j] * invN - mean * mean;
    const float s    = gamma[j] * rsqrtf(var + BN_EPS);
    sc_sh[j]        = s;
    sc_sh[COUT + j] = beta[j] - mean * s;
}

// ---------------- kernel 3: apply BN in place on d_out ----------------
__global__ __launch_bounds__(256) void k_apply(float* __restrict__ x,
                                               const float* __restrict__ sc_sh,
                                               int total4) {
    __shared__ float s[COUT], sh[COUT];
    if (threadIdx.x < COUT) {
        s[threadIdx.x]  = sc_sh[threadIdx.x];
        sh[threadIdx.x] = sc_sh[COUT + threadIdx.x];
    }
    __syncthreads();
    const int stride = gridDim.x * blockDim.x;
    for (int idx = blockIdx.x * blockDim.x + threadIdx.x; idx < total4; idx += stride) {
        float4 v = ((const float4*)x)[idx];
        const int j = (idx * 4) & (COUT - 1);  // COUT divisible by 4: j..j+3 in-row
        v.x = fmaf(v.x, s[j],     sh[j]);
        v.y = fmaf(v.y, s[j + 1], sh[j + 1]);
        v.z = fmaf(v.z, s[j + 2], sh[j + 2]);
        v.w = fmaf(v.w, s[j + 3], sh[j + 3]);
        ((float4*)x)[idx] = v;
    }
}

extern "C" void kernel_launch(void* const* d_in, const int* in_sizes, int n_in,
                              void* d_out, int out_size, void* d_ws, size_t ws_size,
                              hipStream_t stream) {
    const float* inputs     = (const float*)d_in[0];
    const float* sw         = (const float*)d_in[1];
    const float* dw         = (const float*)d_in[2];
    const float* bias       = (const float*)d_in[3];
    const float* gamma      = (const float*)d_in[4];
    const float* beta       = (const float*)d_in[5];
    const int*   nn_count   = (const int*)d_in[6];
    const int*   nn_index   = (const int*)d_in[7];
    const int*   filt_index = (const int*)d_in[8];

    const int N = in_sizes[0] / CIN;           // 65536
    float* x     = (float*)d_out;              // pre-BN activations, then final out
    float* stats = (float*)d_ws;               // 128 floats
    float* sc_sh = (float*)d_ws + 128;         // 128 floats

    k_zero<<<1, 128, 0, stream>>>(stats);

    const int pts_per_block = 4 * PPW;         // 4 waves x 4 points
    k_conv<<<N / pts_per_block, 256, 0, stream>>>(
        inputs, sw, dw, bias, nn_count, nn_index, filt_index, x, stats);

    k_finalize<<<1, COUT, 0, stream>>>(stats, gamma, beta, sc_sh, 1.0f / (float)N);

    const int total4 = N * COUT / 4;
    k_apply<<<2048, 256, 0, stream>>>(x, sc_sh, total4);
}

// Round 3
// 140.071 us; speedup vs baseline: 1.0759x; 1.0759x over previous
//
#include <hip/hip_runtime.h>
#include <math.h>

#define KMAX   32
#define CIN    64
#define COUT   64
#define NKERN  27
#define PPW    8          // points per wave
constexpr float BN_EPS = 1e-5f;

typedef _Float16 f16;
typedef _Float16 f16x2 __attribute__((ext_vector_type(2)));

// ---------------- kernel 0: zero the stats accumulator ----------------
__global__ void k_zero(float* stats) {
    stats[threadIdx.x] = 0.0f;   // 128 threads: [0..63]=sum, [64..127]=sumsq
}

// ---------------- kernel A: convert inputs f32 -> f16 -----------------
__global__ __launch_bounds__(256) void k_cvt(const float* __restrict__ in,
                                             f16* __restrict__ out, int total4) {
    const int stride = gridDim.x * blockDim.x;
    for (int i = blockIdx.x * blockDim.x + threadIdx.x; i < total4; i += stride) {
        const float4 v = ((const float4*)in)[i];
        f16x2 a = { (f16)v.x, (f16)v.y };
        f16x2 b = { (f16)v.z, (f16)v.w };
        uint2 u;
        u.x = *(const unsigned int*)&a;
        u.y = *(const unsigned int*)&b;
        ((uint2*)out)[i] = u;                  // 8B store
    }
}

// ---------------- kernel 1: gather-conv + 64x64 matmul + relu --------
// 4 waves x PPW points per block. Gathers unrolled x4 (4 rows in flight).
// dw in LDS as packed f16 pairs (8KB); matmul via v_dot2_f32_f16.
template <int GATHER_F16>
__global__ __launch_bounds__(256, 8) void k_conv(
    const void*  __restrict__ gather_src,  // f16[N,64] or f32[N,64]
    const float* __restrict__ sw,          // [27, 64, 1]
    const float* __restrict__ dw,          // [64, 64]
    const float* __restrict__ bias,        // [1, 64]
    const int*   __restrict__ nn_count,    // [N]
    const int*   __restrict__ nn_index,    // [N, 32]
    const int*   __restrict__ filt_index,  // [N, 32]
    float*       __restrict__ xout,        // [N, 64]  pre-BN (relu'd)
    float*       __restrict__ stats)       // [128]
{
    __shared__ float sw_lds[NKERN * CIN];          // 6.75 KB
    __shared__ f16x2 dw_lds[(CIN / 2) * COUT];     // 8 KB: [c2][j] = (dw[2c2][j], dw[2c2+1][j])
    __shared__ f16   sp_lds[4][CIN];               // 0.5 KB per-wave sp broadcast
    __shared__ float red[2][4][COUT];              // 2 KB stats reduction

    const int tid = threadIdx.x;
    for (int i = tid; i < NKERN * CIN; i += 256) sw_lds[i] = sw[i];
    for (int i = tid; i < (CIN / 2) * COUT; i += 256) {
        const int c2 = i >> 6, j = i & 63;
        f16x2 w = { (f16)dw[(2 * c2) * COUT + j], (f16)dw[(2 * c2 + 1) * COUT + j] };
        dw_lds[i] = w;
    }
    __syncthreads();

    const int wave = tid >> 6;
    const int lane = tid & 63;
    const int base = blockIdx.x * (4 * PPW) + wave * PPW;
    const float b = bias[lane];
    float sum = 0.0f, sumsq = 0.0f;

    const f16*   gh = (const f16*)gather_src;
    const float* gf = (const float*)gather_src;

    for (int p = 0; p < PPW; ++p) {
        const int n   = base + p;
        const int cnt = nn_count[n];
        const int* __restrict__ ni = nn_index   + (size_t)n * KMAX;
        const int* __restrict__ fi = filt_index + (size_t)n * KMAX;

        float a0 = 0.f, a1 = 0.f, a2 = 0.f, a3 = 0.f;
        int k = 0;
        for (; k + 4 <= cnt; k += 4) {
            const int i0 = ni[k], i1 = ni[k + 1], i2 = ni[k + 2], i3 = ni[k + 3];
            const int f0 = fi[k], f1 = fi[k + 1], f2 = fi[k + 2], f3 = fi[k + 3];
            float g0, g1, g2, g3;
            if (GATHER_F16) {
                g0 = (float)gh[(size_t)i0 * CIN + lane];
                g1 = (float)gh[(size_t)i1 * CIN + lane];
                g2 = (float)gh[(size_t)i2 * CIN + lane];
                g3 = (float)gh[(size_t)i3 * CIN + lane];
            } else {
                g0 = gf[(size_t)i0 * CIN + lane];
                g1 = gf[(size_t)i1 * CIN + lane];
                g2 = gf[(size_t)i2 * CIN + lane];
                g3 = gf[(size_t)i3 * CIN + lane];
            }
            a0 = fmaf(g0, sw_lds[f0 * CIN + lane], a0);
            a1 = fmaf(g1, sw_lds[f1 * CIN + lane], a1);
            a2 = fmaf(g2, sw_lds[f2 * CIN + lane], a2);
            a3 = fmaf(g3, sw_lds[f3 * CIN + lane], a3);
        }
        for (; k < cnt; ++k) {
            const float g = GATHER_F16 ? (float)gh[(size_t)ni[k] * CIN + lane]
                                       : gf[(size_t)ni[k] * CIN + lane];
            a0 = fmaf(g, sw_lds[fi[k] * CIN + lane], a0);
        }

        const float spv = (a0 + a1 + a2 + a3) / (float)cnt;

        // broadcast sp across wave via LDS as f16 (wave-lockstep, no barrier)
        sp_lds[wave][lane] = (f16)spv;
        const f16x2* sp2 = (const f16x2*)sp_lds[wave];
        float xv = b;
        #pragma unroll
        for (int c2 = 0; c2 < CIN / 2; ++c2) {
            const f16x2 s2 = sp2[c2];                    // broadcast read
            const f16x2 w2 = dw_lds[c2 * COUT + lane];   // 2 lanes/bank: free
#if __has_builtin(__builtin_amdgcn_fdot2)
            xv = __builtin_amdgcn_fdot2(s2, w2, xv, false);
#else
            xv = fmaf((float)s2.x, (float)w2.x, xv);
            xv = fmaf((float)s2.y, (float)w2.y, xv);
#endif
        }
        xv = fmaxf(xv, 0.0f);

        xout[(size_t)n * COUT + lane] = xv;
        sum   += xv;
        sumsq += xv * xv;
    }

    red[0][wave][lane] = sum;
    red[1][wave][lane] = sumsq;
    __syncthreads();
    if (wave == 0) {
        float s = red[0][0][lane] + red[0][1][lane] + red[0][2][lane] + red[0][3][lane];
        float q = red[1][0][lane] + red[1][1][lane] + red[1][2][lane] + red[1][3][lane];
        atomicAdd(&stats[lane], s);
        atomicAdd(&stats[COUT + lane], q);
    }
}

// ---------------- kernel 2: finalize BN scale/shift -------------------
__global__ void k_finalize(const float* __restrict__ stats,
                           const float* __restrict__ gamma,
                           const float* __restrict__ beta,
                           float* __restrict__ sc_sh, float invN) {
    const int j = threadIdx.x;               // 64 threads
    const float mean = stats[j] * invN;
    const float var  = stats[COUT + j] * invN - mean * mean;
    const float s    = gamma[j] * rsqrtf(var + BN_EPS);
    sc_sh[j]        = s;
    sc_sh[COUT + j] = beta[j] - mean * s;
}

// ---------------- kernel 3: apply BN in place on d_out ----------------
__global__ __launch_bounds__(256) void k_apply(float* __restrict__ x,
                                               const float* __restrict__ sc_sh,
                                               int total4) {
    __shared__ float s[COUT], sh[COUT];
    if (threadIdx.x < COUT) {
        s[threadIdx.x]  = sc_sh[threadIdx.x];
        sh[threadIdx.x] = sc_sh[COUT + threadIdx.x];
    }
    __syncthreads();
    const int stride = gridDim.x * blockDim.x;
    for (int idx = blockIdx.x * blockDim.x + threadIdx.x; idx < total4; idx += stride) {
        float4 v = ((const float4*)x)[idx];
        const int j = (idx * 4) & (COUT - 1);  // COUT divisible by 4: j..j+3 in-row
        v.x = fmaf(v.x, s[j],     sh[j]);
        v.y = fmaf(v.y, s[j + 1], sh[j + 1]);
        v.z = fmaf(v.z, s[j + 2], sh[j + 2]);
        v.w = fmaf(v.w, s[j + 3], sh[j + 3]);
        ((float4*)x)[idx] = v;
    }
}

extern "C" void kernel_launch(void* const* d_in, const int* in_sizes, int n_in,
                              void* d_out, int out_size, void* d_ws, size_t ws_size,
                              hipStream_t stream) {
    const float* inputs     = (const float*)d_in[0];
    const float* sw         = (const float*)d_in[1];
    const float* dw         = (const float*)d_in[2];
    const float* bias       = (const float*)d_in[3];
    const float* gamma      = (const float*)d_in[4];
    const float* beta       = (const float*)d_in[5];
    const int*   nn_count   = (const int*)d_in[6];
    const int*   nn_index   = (const int*)d_in[7];
    const int*   filt_index = (const int*)d_in[8];

    const int N = in_sizes[0] / CIN;           // 65536
    float* x     = (float*)d_out;              // pre-BN activations, then final out
    float* stats = (float*)d_ws;               // [0..127]
    float* sc_sh = (float*)d_ws + 128;         // [128..255]
    f16*   in_h  = (f16*)((float*)d_ws + 256); // N*64 halves

    const size_t ws_needed = 256 * sizeof(float) + (size_t)N * CIN * sizeof(f16);

    k_zero<<<1, 128, 0, stream>>>(stats);

    const int blocks = N / (4 * PPW);          // 2048
    if (ws_size >= ws_needed) {
        k_cvt<<<2048, 256, 0, stream>>>(inputs, in_h, N * CIN / 4);
        k_conv<1><<<blocks, 256, 0, stream>>>(
            in_h, sw, dw, bias, nn_count, nn_index, filt_index, x, stats);
    } else {
        k_conv<0><<<blocks, 256, 0, stream>>>(
            inputs, sw, dw, bias, nn_count, nn_index, filt_index, x, stats);
    }

    k_finalize<<<1, COUT, 0, stream>>>(stats, gamma, beta, sc_sh, 1.0f / (float)N);

    const int total4 = N * COUT / 4;
    k_apply<<<2048, 256, 0, stream>>>(x, sc_sh, total4);
}

// Round 4
// 96.231 us; speedup vs baseline: 1.5661x; 1.4556x over previous
//
#include <hip/hip_runtime.h>
#include <math.h>

#define KMAX   32
#define CIN    64
#define COUT   64
#define NKERN  27
#define PPW    8          // points per wave
constexpr float BN_EPS = 1e-5f;

typedef _Float16 f16;
typedef _Float16 f16x2 __attribute__((ext_vector_type(2)));

// ---------------- kernel 0: zero the stats accumulator ----------------
__global__ void k_zero(float* stats) {
    stats[threadIdx.x] = 0.0f;   // 128 threads: [0..63]=sum, [64..127]=sumsq
}

// ---------------- kernel A: convert inputs f32 -> f16 -----------------
__global__ __launch_bounds__(256) void k_cvt(const float* __restrict__ in,
                                             f16* __restrict__ out, int total4) {
    const int stride = gridDim.x * blockDim.x;
    for (int i = blockIdx.x * blockDim.x + threadIdx.x; i < total4; i += stride) {
        const float4 v = ((const float4*)in)[i];
        f16x2 a = { (f16)v.x, (f16)v.y };
        f16x2 b = { (f16)v.z, (f16)v.w };
        uint2 u;
        u.x = *(const unsigned int*)&a;
        u.y = *(const unsigned int*)&b;
        ((uint2*)out)[i] = u;                  // 8B store
    }
}

// ---------------- kernel 1: gather-conv + 64x64 matmul + relu --------
// 4 waves x PPW points. Per point: load all 32 indices via int4, issue 16
// (or 32) independent gathers before any use -> deep MLP. Invalid slots are
// valid-but-garbage indices; masked by (k < cnt).
__global__ __launch_bounds__(256, 4) void k_conv(
    const f16*   __restrict__ gh,          // f16[N,64]
    const float* __restrict__ sw,          // [27, 64, 1]
    const float* __restrict__ dw,          // [64, 64]
    const float* __restrict__ bias,        // [1, 64]
    const int*   __restrict__ nn_count,    // [N]
    const int*   __restrict__ nn_index,    // [N, 32]
    const int*   __restrict__ filt_index,  // [N, 32]
    float*       __restrict__ xout,        // [N, 64]  pre-BN (relu'd)
    float*       __restrict__ stats)       // [128]
{
    __shared__ float sw_lds[NKERN * CIN];          // 6.75 KB
    __shared__ f16x2 dw_lds[(CIN / 2) * COUT];     // 8 KB
    __shared__ f16   sp_lds[4][CIN];               // 0.5 KB
    __shared__ float red[2][4][COUT];              // 2 KB

    const int tid = threadIdx.x;
    for (int i = tid; i < NKERN * CIN; i += 256) sw_lds[i] = sw[i];
    for (int i = tid; i < (CIN / 2) * COUT; i += 256) {
        const int c2 = i >> 6, j = i & 63;
        f16x2 w = { (f16)dw[(2 * c2) * COUT + j], (f16)dw[(2 * c2 + 1) * COUT + j] };
        dw_lds[i] = w;
    }
    __syncthreads();

    const int wave = tid >> 6;
    const int lane = tid & 63;
    const int base = blockIdx.x * (4 * PPW) + wave * PPW;
    const float b = bias[lane];
    float sum = 0.0f, sumsq = 0.0f;

    for (int p = 0; p < PPW; ++p) {
        const int n   = base + p;
        const int cnt = nn_count[n];
        const int4* __restrict__ ni4 = (const int4*)(nn_index   + (size_t)n * KMAX);
        const int4* __restrict__ fi4 = (const int4*)(filt_index + (size_t)n * KMAX);

        int idx[16], flt[16];
        *(int4*)&idx[0]  = ni4[0]; *(int4*)&idx[4]  = ni4[1];
        *(int4*)&idx[8]  = ni4[2]; *(int4*)&idx[12] = ni4[3];
        *(int4*)&flt[0]  = fi4[0]; *(int4*)&flt[4]  = fi4[1];
        *(int4*)&flt[8]  = fi4[2]; *(int4*)&flt[12] = fi4[3];

        f16 g[16];
        #pragma unroll
        for (int k = 0; k < 16; ++k)                 // 16 independent loads
            g[k] = gh[(size_t)idx[k] * CIN + lane];

        float a0 = 0.f, a1 = 0.f, a2 = 0.f, a3 = 0.f;
        #pragma unroll
        for (int k = 0; k < 16; ++k) {
            const float gv = (k < cnt) ? (float)g[k] : 0.0f;
            float& a = (k & 3) == 0 ? a0 : (k & 3) == 1 ? a1 : (k & 3) == 2 ? a2 : a3;
            a = fmaf(gv, sw_lds[flt[k] * CIN + lane], a);
        }

        if (cnt > 16) {                              // wave-uniform branch
            int idxh[16], flth[16];
            *(int4*)&idxh[0]  = ni4[4]; *(int4*)&idxh[4]  = ni4[5];
            *(int4*)&idxh[8]  = ni4[6]; *(int4*)&idxh[12] = ni4[7];
            *(int4*)&flth[0]  = fi4[4]; *(int4*)&flth[4]  = fi4[5];
            *(int4*)&flth[8]  = fi4[6]; *(int4*)&flth[12] = fi4[7];

            f16 gb[16];
            #pragma unroll
            for (int k = 0; k < 16; ++k)
                gb[k] = gh[(size_t)idxh[k] * CIN + lane];

            #pragma unroll
            for (int k = 0; k < 16; ++k) {
                const float gv = (k + 16 < cnt) ? (float)gb[k] : 0.0f;
                float& a = (k & 3) == 0 ? a0 : (k & 3) == 1 ? a1 : (k & 3) == 2 ? a2 : a3;
                a = fmaf(gv, sw_lds[flth[k] * CIN + lane], a);
            }
        }

        const float spv = (a0 + a1 + a2 + a3) / (float)cnt;

        // broadcast sp across wave via LDS as f16 (wave-lockstep, no barrier)
        sp_lds[wave][lane] = (f16)spv;
        const f16x2* sp2 = (const f16x2*)sp_lds[wave];
        float xv = b;
        #pragma unroll
        for (int c2 = 0; c2 < CIN / 2; ++c2) {
            const f16x2 s2 = sp2[c2];                    // broadcast read
            const f16x2 w2 = dw_lds[c2 * COUT + lane];   // 2 lanes/bank: free
#if __has_builtin(__builtin_amdgcn_fdot2)
            xv = __builtin_amdgcn_fdot2(s2, w2, xv, false);
#else
            xv = fmaf((float)s2.x, (float)w2.x, xv);
            xv = fmaf((float)s2.y, (float)w2.y, xv);
#endif
        }
        xv = fmaxf(xv, 0.0f);

        xout[(size_t)n * COUT + lane] = xv;
        sum   += xv;
        sumsq += xv * xv;
    }

    red[0][wave][lane] = sum;
    red[1][wave][lane] = sumsq;
    __syncthreads();
    if (wave == 0) {
        float s = red[0][0][lane] + red[0][1][lane] + red[0][2][lane] + red[0][3][lane];
        float q = red[1][0][lane] + red[1][1][lane] + red[1][2][lane] + red[1][3][lane];
        atomicAdd(&stats[lane], s);
        atomicAdd(&stats[COUT + lane], q);
    }
}

// ---------------- kernel 2: finalize BN scale/shift -------------------
__global__ void k_finalize(const float* __restrict__ stats,
                           const float* __restrict__ gamma,
                           const float* __restrict__ beta,
                           float* __restrict__ sc_sh, float invN) {
    const int j = threadIdx.x;               // 64 threads
    const float mean = stats[j] * invN;
    const float var  = stats[COUT + j] * invN - mean * mean;
    const float s    = gamma[j] * rsqrtf(var + BN_EPS);
    sc_sh[j]        = s;
    sc_sh[COUT + j] = beta[j] - mean * s;
}

// ---------------- kernel 3: apply BN in place on d_out ----------------
__global__ __launch_bounds__(256) void k_apply(float* __restrict__ x,
                                               const float* __restrict__ sc_sh,
                                               int total4) {
    __shared__ float s[COUT], sh[COUT];
    if (threadIdx.x < COUT) {
        s[threadIdx.x]  = sc_sh[threadIdx.x];
        sh[threadIdx.x] = sc_sh[COUT + threadIdx.x];
    }
    __syncthreads();
    const int stride = gridDim.x * blockDim.x;
    for (int idx = blockIdx.x * blockDim.x + threadIdx.x; idx < total4; idx += stride) {
        float4 v = ((const float4*)x)[idx];
        const int j = (idx * 4) & (COUT - 1);
        v.x = fmaf(v.x, s[j],     sh[j]);
        v.y = fmaf(v.y, s[j + 1], sh[j + 1]);
        v.z = fmaf(v.z, s[j + 2], sh[j + 2]);
        v.w = fmaf(v.w, s[j + 3], sh[j + 3]);
        ((float4*)x)[idx] = v;
    }
}

extern "C" void kernel_launch(void* const* d_in, const int* in_sizes, int n_in,
                              void* d_out, int out_size, void* d_ws, size_t ws_size,
                              hipStream_t stream) {
    const float* inputs     = (const float*)d_in[0];
    const float* sw         = (const float*)d_in[1];
    const float* dw         = (const float*)d_in[2];
    const float* bias       = (const float*)d_in[3];
    const float* gamma      = (const float*)d_in[4];
    const float* beta       = (const float*)d_in[5];
    const int*   nn_count   = (const int*)d_in[6];
    const int*   nn_index   = (const int*)d_in[7];
    const int*   filt_index = (const int*)d_in[8];

    const int N = in_sizes[0] / CIN;           // 65536
    float* x     = (float*)d_out;              // pre-BN activations, then final out
    float* stats = (float*)d_ws;               // [0..127]
    float* sc_sh = (float*)d_ws + 128;         // [128..255]
    f16*   in_h  = (f16*)((float*)d_ws + 256); // N*64 halves

    k_zero<<<1, 128, 0, stream>>>(stats);
    k_cvt<<<2048, 256, 0, stream>>>(inputs, in_h, N * CIN / 4);

    const int blocks = N / (4 * PPW);          // 2048
    k_conv<<<blocks, 256, 0, stream>>>(
        in_h, sw, dw, bias, nn_count, nn_index, filt_index, x, stats);

    k_finalize<<<1, COUT, 0, stream>>>(stats, gamma, beta, sc_sh, 1.0f / (float)N);

    const int total4 = N * COUT / 4;
    k_apply<<<2048, 256, 0, stream>>>(x, sc_sh, total4);
}